// Round 4
// baseline (167.984 us; speedup 1.0000x reference)
//
#include <hip/hip_runtime.h>

// SupConLoss, B=8192, D=128, T=5.0 — round 4.
//   m_i = s_ii = ||f_i||^2/T (ref's row max IS the diagonal; exact shift)
//   Z_i = sum_{j!=i} exp(s_ij - s_ii)   — bf16 MFMA flash pass
//   A_i = sum_{j!=i, label match} s_ij  — in-loop (cmp+cndmask+add), NO class-sum atomics
//   cnt_i = hist[label_i] - 1           — LDS histogram in prep
//   term_i = (A_i - cnt*s_ii)/cnt - log(1e-12+Z_i); loss = -mean(term_i | cnt>0)
// 2 dispatches; finalize folded into main via ticket atomics (R3-proven pattern).

#define BN 8192
#define DK 128
#define INV_T 0.2f
#define LOG2E 1.4426950408889634f

#define GX 64                 // row blocks, 128 rows each (4 waves * 32 rows)
#define GY 32                 // col chunks
#define CHUNK_COLS (BN / GY)  // 256
#define JT (CHUNK_COLS / 16)  // 16

typedef __attribute__((ext_vector_type(8))) short bf16x8;   // 8 bf16 = 4 VGPRs
typedef __attribute__((ext_vector_type(4))) float f32x4;

// ---- ws layout (bytes) ----
#define OFF_FB   0                          // bf16 features, 2 MB
#define OFF_SII  (BN * DK * 2)              // float[BN]
#define OFF_CNT  (OFF_SII + BN * 4)         // int[128]
#define OFF_Z    (OFF_CNT + 512)            // float[BN]  (zeroed by prep)
#define OFF_RA   (OFF_Z + BN * 4)           // float[BN]  (zeroed by prep)
#define OFF_TKT  (OFF_RA + BN * 4)          // int[GX]    (zeroed by prep blk 0)
#define OFF_MISC (OFF_TKT + GX * 4)         // int gTicket; float lossAcc

__device__ __forceinline__ unsigned short f2bf(float f) {
    unsigned u = __builtin_bit_cast(unsigned, f);
    u += 0x7fffu + ((u >> 16) & 1u);
    return (unsigned short)(u >> 16);
}

// prep: cast F->bf16, per-row s_ii, zero accumulators, label histogram.
__global__ __launch_bounds__(256) void supcon_prep(const float* __restrict__ F,
                                                   const int* __restrict__ labels,
                                                   unsigned short* __restrict__ Fb,
                                                   float* __restrict__ sii,
                                                   int* __restrict__ counts,
                                                   float* __restrict__ zeroArr,  // Zrow+rowA
                                                   int* __restrict__ rbT,
                                                   int* __restrict__ gT,
                                                   float* __restrict__ lossA) {
    const int t   = threadIdx.x;
    const int idx = blockIdx.x * 256 + t;             // float4 index, < BN*DK/4
    float4 v = ((const float4*)F)[idx];

    ushort4 o;
    o.x = f2bf(v.x); o.y = f2bf(v.y); o.z = f2bf(v.z); o.w = f2bf(v.w);
    ((ushort4*)Fb)[idx] = o;

    float sq = v.x * v.x + v.y * v.y + v.z * v.z + v.w * v.w;
    sq += __shfl_xor(sq, 1);  sq += __shfl_xor(sq, 2);  sq += __shfl_xor(sq, 4);
    sq += __shfl_xor(sq, 8);  sq += __shfl_xor(sq, 16);
    if ((t & 31) == 0) sii[idx >> 5] = sq * INV_T;    // 32 float4 per row

    // zero Zrow+rowA: 16384 floats / 1024 blocks = 16 each
    if (t < 16) zeroArr[blockIdx.x * 16 + t] = 0.f;

    if (blockIdx.x == 0) {
        __shared__ int hist[128];
        if (t < GX) rbT[t] = 0;
        if (t == 0) { *gT = 0; *lossA = 0.f; }
        if (t < 128) hist[t] = 0;
        __syncthreads();
#pragma unroll
        for (int i = 0; i < 32; ++i) atomicAdd(&hist[labels[t + 256 * i]], 1);
        __syncthreads();
        if (t < 128) counts[t] = hist[t];
    }
}

__global__ __launch_bounds__(256, 4) void supcon_main(
    const short* __restrict__ Fb, const int* __restrict__ labels,
    const float* __restrict__ sii, const int* __restrict__ counts,
    float* __restrict__ Zrow, float* __restrict__ rowA,
    int* __restrict__ rbT, int* __restrict__ gT,
    float* __restrict__ lossA, float* __restrict__ out)
{
    const int tid  = threadIdx.x;
    const int wave = tid >> 6, lane = tid & 63;
    const int quad = lane >> 4, l16 = lane & 15;
    const int bx = blockIdx.x, by = blockIdx.y;
    const int rowBase = bx * 128 + wave * 32;   // RT=2: 32 rows/wave
    const int colBase = by * CHUNK_COLS;

    __shared__ int   tkt;
    __shared__ float ss[4];

    // A fragments (verified 16x16x32 layout): elem = F[base+(lane&15)][kt*32+quad*8+j]
    bf16x8 a[2][4];
#pragma unroll
    for (int rt = 0; rt < 2; ++rt)
#pragma unroll
        for (int kt = 0; kt < 4; ++kt)
            a[rt][kt] = *(const bf16x8*)(Fb + (size_t)(rowBase + rt * 16 + l16) * DK
                                            + kt * 32 + quad * 8);

    // per-lane rows in C/D layout: row = rowBase + rt*16 + quad*4 + r
    float nc2[2][4];
    int   rlbl[2][4];
#pragma unroll
    for (int rt = 0; rt < 2; ++rt)
#pragma unroll
        for (int r = 0; r < 4; ++r) {
            const int row = rowBase + rt * 16 + quad * 4 + r;
            nc2[rt][r]  = -sii[row] * LOG2E;
            rlbl[rt][r] = labels[row];
        }

    float Z[2][4], A[2][4];
#pragma unroll
    for (int rt = 0; rt < 2; ++rt)
#pragma unroll
        for (int r = 0; r < 4; ++r) { Z[rt][r] = 0.f; A[rt][r] = 0.f; }

    const float K2 = INV_T * LOG2E;

    // prefetch tile 0
    bf16x8 bc[4];
#pragma unroll
    for (int kt = 0; kt < 4; ++kt)
        bc[kt] = *(const bf16x8*)(Fb + (size_t)(colBase + l16) * DK + kt * 32 + quad * 8);
    int clbl = labels[colBase + l16];

    for (int jt = 0; jt < JT; ++jt) {
        // prefetch next tile (wraps to tile 0 on last iter — harmless, cached)
        const int j0n = colBase + ((jt + 1) & (JT - 1)) * 16;
        bf16x8 bn[4];
#pragma unroll
        for (int kt = 0; kt < 4; ++kt)
            bn[kt] = *(const bf16x8*)(Fb + (size_t)(j0n + l16) * DK + kt * 32 + quad * 8);
        const int clbln = labels[j0n + l16];

#pragma unroll
        for (int rt = 0; rt < 2; ++rt) {
            f32x4 acc = {0.f, 0.f, 0.f, 0.f};
#pragma unroll
            for (int kt = 0; kt < 4; ++kt)
                acc = __builtin_amdgcn_mfma_f32_16x16x32_bf16(a[rt][kt], bc[kt], acc, 0, 0, 0);

            const bool dt = (colBase + jt * 16 == rowBase + rt * 16);  // wave-uniform
#pragma unroll
            for (int r = 0; r < 4; ++r) {
                const float s = acc[r];
                float e  = __builtin_amdgcn_exp2f(fmaf(s, K2, nc2[rt][r]));
                float am = (clbl == rlbl[rt][r]) ? s : 0.f;
                if (dt && (l16 == quad * 4 + r)) { e = 0.f; am = 0.f; }  // self-contrast
                Z[rt][r] += e;
                A[rt][r] += am;
            }
        }
#pragma unroll
        for (int kt = 0; kt < 4; ++kt) bc[kt] = bn[kt];
        clbl = clbln;
    }

    // reduce across the 16 columns each lane covers; accumulate per row
#pragma unroll
    for (int rt = 0; rt < 2; ++rt)
#pragma unroll
        for (int r = 0; r < 4; ++r) {
            float z = Z[rt][r], aa = A[rt][r];
            z  += __shfl_xor(z, 1);  z  += __shfl_xor(z, 2);
            z  += __shfl_xor(z, 4);  z  += __shfl_xor(z, 8);
            aa += __shfl_xor(aa, 1); aa += __shfl_xor(aa, 2);
            aa += __shfl_xor(aa, 4); aa += __shfl_xor(aa, 8);
            if (l16 == 0) {
                const int row = rowBase + rt * 16 + quad * 4 + r;
                unsafeAtomicAdd(&Zrow[row], z);
                unsafeAtomicAdd(&rowA[row], aa);
            }
        }

    // ticket: last of the GY chunk-blocks for this row-block finalizes its 128 rows
    __syncthreads();                       // drains this block's atomics
    if (tid == 0) { __threadfence(); tkt = atomicAdd(&rbT[bx], 1); }
    __syncthreads();
    if (tkt == GY - 1) {
        float term = 0.f;
        if (tid < 128) {
            const int i  = bx * 128 + tid;
            const float Zv = unsafeAtomicAdd(&Zrow[i], 0.f);   // coherent read
            const float Av = unsafeAtomicAdd(&rowA[i], 0.f);
            const int   c  = counts[labels[i]] - 1;
            if (c > 0)
                term = (Av * INV_T - (float)c * sii[i]) / (float)c
                       - __logf(1e-12f + Zv);
        }
#pragma unroll
        for (int h = 1; h < 64; h <<= 1) term += __shfl_xor(term, h);
        if (lane == 0) ss[wave] = term;
        __syncthreads();
        if (tid == 0) {
            unsafeAtomicAdd(lossA, ss[0] + ss[1] + ss[2] + ss[3]);
            __threadfence();
            const int g = atomicAdd(gT, 1);
            if (g == GX - 1)
                out[0] = -unsafeAtomicAdd(lossA, 0.f) * (1.0f / BN);
        }
    }
}

extern "C" void kernel_launch(void* const* d_in, const int* in_sizes, int n_in,
                              void* d_out, int out_size, void* d_ws, size_t ws_size,
                              hipStream_t stream) {
    const float* F      = (const float*)d_in[0];
    const int*   labels = (const int*)d_in[1];
    float* out = (float*)d_out;
    char*  ws  = (char*)d_ws;

    unsigned short* Fb     = (unsigned short*)(ws + OFF_FB);
    float*          sii    = (float*)(ws + OFF_SII);
    int*            counts = (int*)(ws + OFF_CNT);
    float*          Zrow   = (float*)(ws + OFF_Z);
    float*          rowA   = (float*)(ws + OFF_RA);
    int*            rbT    = (int*)(ws + OFF_TKT);
    int*            gT     = (int*)(ws + OFF_MISC);
    float*          lossA  = (float*)(ws + OFF_MISC + 4);

    supcon_prep<<<BN * DK / 4 / 256, 256, 0, stream>>>(F, labels, Fb, sii, counts,
                                                       Zrow, rbT, gT, lossA);
    supcon_main<<<dim3(GX, GY), 256, 0, stream>>>((const short*)Fb, labels, sii, counts,
                                                  Zrow, rowA, rbT, gT, lossA, out);
}

// Round 5
// 132.681 us; speedup vs baseline: 1.2661x; 1.2661x over previous
//
#include <hip/hip_runtime.h>

// SupConLoss, B=8192, D=128, T=5.0 — round 5.
// R3-proven main body (RT=4, plain loads) + occupancy fix + register diet.
//   Z_i  = sum_{j!=i} exp(s_ij)        (UNSHIFTED; s_ij ~ N(0,2.26), max ~13 -> no overflow)
//   log(sum exp(s_ij - s_ii)) = log(Z_i) - s_ii   (shift applied analytically at finalize)
//   A_i  = sum_{j!=i, match} acc_ij    (raw dots; * INV_T at finalize)
//   term_i = (A*INV_T - c*s_ii)/c - (log(Z) - s_ii);  loss = -mean(term | c>0)
// Labels byte-packed (labB) so one VGPR holds 4 consecutive rows' labels.

#define BN 8192
#define DK 128
#define INV_T 0.2f
#define LOG2E 1.4426950408889634f

#define GX 32                 // row blocks, 256 rows each (4 waves * 64 rows, RT=4)
#define GY 32                 // col chunks
#define CHUNK_COLS (BN / GY)  // 256
#define JT (CHUNK_COLS / 16)  // 16

typedef __attribute__((ext_vector_type(8))) short bf16x8;   // 8 bf16 = 4 VGPRs
typedef __attribute__((ext_vector_type(4))) float f32x4;

// ---- ws layout (bytes) ----
#define OFF_FB   0                          // bf16 features, 2 MB
#define OFF_SII  (BN * DK * 2)              // float[BN]
#define OFF_CNT  (OFF_SII + BN * 4)         // int[128]
#define OFF_LB   (OFF_CNT + 512)            // uchar[BN] packed labels
#define OFF_Z    (OFF_LB + BN)              // float[BN]  (zeroed by prep)
#define OFF_RA   (OFF_Z + BN * 4)           // float[BN]  (zeroed by prep)
#define OFF_TKT  (OFF_RA + BN * 4)          // int[GX]    (zeroed by prep blk 0)
#define OFF_MISC (OFF_TKT + GX * 4)         // int gTicket; float lossAcc

__device__ __forceinline__ unsigned short f2bf(float f) {
    unsigned u = __builtin_bit_cast(unsigned, f);
    u += 0x7fffu + ((u >> 16) & 1u);
    return (unsigned short)(u >> 16);
}

// prep: cast F->bf16, per-row s_ii, byte labels, zero accumulators, histogram.
__global__ __launch_bounds__(256) void supcon_prep(const float* __restrict__ F,
                                                   const int* __restrict__ labels,
                                                   unsigned short* __restrict__ Fb,
                                                   float* __restrict__ sii,
                                                   int* __restrict__ counts,
                                                   unsigned char* __restrict__ labB,
                                                   float* __restrict__ zeroArr,  // Zrow+rowA
                                                   int* __restrict__ rbT,
                                                   int* __restrict__ gT,
                                                   float* __restrict__ lossA) {
    const int t   = threadIdx.x;
    const int idx = blockIdx.x * 256 + t;             // float4 index, < BN*DK/4 = 256K
    float4 v = ((const float4*)F)[idx];

    ushort4 o;
    o.x = f2bf(v.x); o.y = f2bf(v.y); o.z = f2bf(v.z); o.w = f2bf(v.w);
    ((ushort4*)Fb)[idx] = o;

    float sq = v.x * v.x + v.y * v.y + v.z * v.z + v.w * v.w;
    sq += __shfl_xor(sq, 1);  sq += __shfl_xor(sq, 2);  sq += __shfl_xor(sq, 4);
    sq += __shfl_xor(sq, 8);  sq += __shfl_xor(sq, 16);
    if ((t & 31) == 0) sii[idx >> 5] = sq * INV_T;    // 32 float4 per row

    // byte-pack labels (first 32 blocks cover BN rows)
    if (blockIdx.x < BN / 256)
        labB[blockIdx.x * 256 + t] = (unsigned char)labels[blockIdx.x * 256 + t];

    // zero Zrow+rowA: 16384 floats / 1024 blocks = 16 each
    if (t < 16) zeroArr[blockIdx.x * 16 + t] = 0.f;

    if (blockIdx.x == 0) {
        __shared__ int hist[128];
        if (t < GX) rbT[t] = 0;
        if (t == 0) { *gT = 0; *lossA = 0.f; }
        if (t < 128) hist[t] = 0;
        __syncthreads();
#pragma unroll
        for (int i = 0; i < 32; ++i) atomicAdd(&hist[labels[t + 256 * i]], 1);
        __syncthreads();
        if (t < 128) counts[t] = hist[t];
    }
}

__global__ __launch_bounds__(256) void supcon_main(
    const short* __restrict__ Fb, const unsigned char* __restrict__ labB,
    const float* __restrict__ sii, const int* __restrict__ counts,
    float* __restrict__ Zrow, float* __restrict__ rowA,
    int* __restrict__ rbT, int* __restrict__ gT,
    float* __restrict__ lossA, float* __restrict__ out)
{
    const int tid  = threadIdx.x;
    const int wave = tid >> 6, lane = tid & 63;
    const int quad = lane >> 4, l16 = lane & 15;
    const int bx = blockIdx.x, by = blockIdx.y;
    const int rowBase = bx * 256 + wave * 64;   // RT=4: 64 rows/wave
    const int colBase = by * CHUNK_COLS;

    __shared__ int   tkt;
    __shared__ float ss[4];

    // A fragments (verified 16x16x32 layout): elem = F[base+(lane&15)][kt*32+quad*8+j]
    bf16x8 a[4][4];
#pragma unroll
    for (int rt = 0; rt < 4; ++rt)
#pragma unroll
        for (int kt = 0; kt < 4; ++kt)
            a[rt][kt] = *(const bf16x8*)(Fb + (size_t)(rowBase + rt * 16 + l16) * DK
                                            + kt * 32 + quad * 8);

    // this lane's C/D rows are quad*4+{0..3} (consecutive) -> 4 labels in one VGPR
    unsigned rlb[4];
#pragma unroll
    for (int rt = 0; rt < 4; ++rt)
        rlb[rt] = *(const unsigned*)(labB + rowBase + rt * 16 + quad * 4);

    float Z[4][4], A[4][4];
#pragma unroll
    for (int rt = 0; rt < 4; ++rt)
#pragma unroll
        for (int r = 0; r < 4; ++r) { Z[rt][r] = 0.f; A[rt][r] = 0.f; }

    const float k2 = INV_T * LOG2E;

    for (int jt = 0; jt < JT; ++jt) {
        const int j0 = colBase + jt * 16;
        bf16x8 b[4];
#pragma unroll
        for (int kt = 0; kt < 4; ++kt)
            b[kt] = *(const bf16x8*)(Fb + (size_t)(j0 + l16) * DK + kt * 32 + quad * 8);
        const unsigned clbl = labB[j0 + l16];     // this lane's column label

#pragma unroll
        for (int rt = 0; rt < 4; ++rt) {
            f32x4 acc = {0.f, 0.f, 0.f, 0.f};
#pragma unroll
            for (int kt = 0; kt < 4; ++kt)
                acc = __builtin_amdgcn_mfma_f32_16x16x32_bf16(a[rt][kt], b[kt], acc, 0, 0, 0);

            const bool dt = (j0 == rowBase + rt * 16);   // wave-uniform diag tile
#pragma unroll
            for (int r = 0; r < 4; ++r) {
                const float s = acc[r];
                float e  = __builtin_amdgcn_exp2f(s * k2);
                bool  mt = (((rlb[rt] >> (8 * r)) & 255u) == clbl);
                if (dt && (l16 == quad * 4 + r)) { e = 0.f; mt = false; }  // self
                Z[rt][r] += e;
                A[rt][r] += mt ? s : 0.f;
            }
        }
    }

    // reduce across the 16 columns each lane covers; accumulate per row
#pragma unroll
    for (int rt = 0; rt < 4; ++rt)
#pragma unroll
        for (int r = 0; r < 4; ++r) {
            float z = Z[rt][r], aa = A[rt][r];
            z  += __shfl_xor(z, 1);  z  += __shfl_xor(z, 2);
            z  += __shfl_xor(z, 4);  z  += __shfl_xor(z, 8);
            aa += __shfl_xor(aa, 1); aa += __shfl_xor(aa, 2);
            aa += __shfl_xor(aa, 4); aa += __shfl_xor(aa, 8);
            if (l16 == 0) {
                const int row = rowBase + rt * 16 + quad * 4 + r;
                unsafeAtomicAdd(&Zrow[row], z);
                unsafeAtomicAdd(&rowA[row], aa);
            }
        }

    // ticket: last of the GY chunk-blocks for this row-block finalizes its 256 rows
    __syncthreads();                       // drains this block's atomics
    if (tid == 0) { __threadfence(); tkt = atomicAdd(&rbT[bx], 1); }
    __syncthreads();
    if (tkt == GY - 1) {
        const int i  = bx * 256 + tid;
        const float Zv = unsafeAtomicAdd(&Zrow[i], 0.f);   // coherent read
        const float Av = unsafeAtomicAdd(&rowA[i], 0.f);
        const int   c  = counts[labB[i]] - 1;
        const float s2 = sii[i];
        float term = 0.f;
        if (c > 0)
            term = (Av * INV_T - (float)c * s2) / (float)c - (__logf(Zv) - s2);
#pragma unroll
        for (int h = 1; h < 64; h <<= 1) term += __shfl_xor(term, h);
        if (lane == 0) ss[wave] = term;
        __syncthreads();
        if (tid == 0) {
            unsafeAtomicAdd(lossA, ss[0] + ss[1] + ss[2] + ss[3]);
            __threadfence();
            const int g = atomicAdd(gT, 1);
            if (g == GX - 1)
                out[0] = -unsafeAtomicAdd(lossA, 0.f) * (1.0f / BN);
        }
    }
}

extern "C" void kernel_launch(void* const* d_in, const int* in_sizes, int n_in,
                              void* d_out, int out_size, void* d_ws, size_t ws_size,
                              hipStream_t stream) {
    const float* F      = (const float*)d_in[0];
    const int*   labels = (const int*)d_in[1];
    float* out = (float*)d_out;
    char*  ws  = (char*)d_ws;

    unsigned short* Fb     = (unsigned short*)(ws + OFF_FB);
    float*          sii    = (float*)(ws + OFF_SII);
    int*            counts = (int*)(ws + OFF_CNT);
    unsigned char*  labB   = (unsigned char*)(ws + OFF_LB);
    float*          Zrow   = (float*)(ws + OFF_Z);
    float*          rowA   = (float*)(ws + OFF_RA);
    int*            rbT    = (int*)(ws + OFF_TKT);
    int*            gT     = (int*)(ws + OFF_MISC);
    float*          lossA  = (float*)(ws + OFF_MISC + 4);

    supcon_prep<<<BN * DK / 4 / 256, 256, 0, stream>>>(F, labels, Fb, sii, counts,
                                                       labB, Zrow, rbT, gT, lossA);
    supcon_main<<<dim3(GX, GY), 256, 0, stream>>>((const short*)Fb, labB, sii, counts,
                                                  Zrow, rowA, rbT, gT, lossA, out);
}